// Round 12
// baseline (190.033 us; speedup 1.0000x reference)
//
#include <hip/hip_runtime.h>
#include <hip/hip_bf16.h>

// HypoNerf fused MLP on MI355X (gfx950). R12 = R10 + 2x2 wave grid.
//  R11 (32x32 MFMA) showed MFMA pipe time is NOT the critical path; the
//  LDS pipe is (~55-65% busy per CU). R10's col-only wave split makes all
//  4 waves read the full h tile (4x amplification). 2x2 split: wave (wr,wc)
//  owns rows [wr*32,+32) x cols [wc*128,+128) -> K-loop ds_reads halve.
//  Cost: each weight frag read by 2 waves (FETCH ~2x, L2-resident, ~46 B/cy
//  per CU < 56 budget). Everything else = R10: 16x16x32 MFMA, MT=64,
//  3 waves/SIMD, pointer-advance streams, parity DS bases, folded final
//  projection, raw barriers, XCD swizzle.

#define H 256
#define MT 64
#define PE_NF 60

typedef __attribute__((ext_vector_type(8))) short s16x8;   // 8 bf16
typedef __attribute__((ext_vector_type(4))) float f32x4;   // MFMA acc

static __device__ __forceinline__ unsigned short f2bf(float v) {
  unsigned int u = __float_as_uint(v);
  return (unsigned short)((u + 0x7FFFu + ((u >> 16) & 1u)) >> 16);
}
// swizzled 16B-chunk index within a 256-elem (32-chunk) row
static __device__ __forceinline__ int hswz(int row, int chunk) {
  return (chunk & ~7) | ((chunk ^ row) & 7);
}

static __device__ __forceinline__ void bar_raw() {
  asm volatile("s_barrier" ::: "memory");
}
static __device__ __forceinline__ void bar_lgkm() {
  asm volatile("s_waitcnt lgkmcnt(0)\n\ts_barrier" ::: "memory");
}

// ---------------------------------------------------------------------------
// Prep: wb (fp32, [K+1][H], last row bias) -> fragment-packed bf16 (R10 fmt).
// pack elem idx for (n, k):  (kt*16 + (n>>4))*512 + (kgrp*16 + (n&15))*8 + j
//   where kt=k>>5, kgrp=(k>>3)&3, j=k&7.
// ---------------------------------------------------------------------------
__global__ __launch_bounds__(256) void prep_weights(
    const float* __restrict__ wb0, const float* __restrict__ wb1,
    const float* __restrict__ wb2, const float* __restrict__ wb3,
    const float* __restrict__ wb4,
    unsigned short* __restrict__ w0p, unsigned short* __restrict__ w14p,
    float* __restrict__ biases) {
  int z = blockIdx.z;
  int li = z >> 4, b = z & 15;
  int k0 = blockIdx.x * 32;
  int n0 = blockIdx.y * 32;
  int Ks;
  const float* src;
  unsigned short* dst;
  if (li == 0) {
    Ks = 120;
    if (k0 >= 128) return;
    src = wb0 + (size_t)b * 121 * H;
    dst = w0p + (size_t)b * 32768;
  } else {
    Ks = 256;
    const float* srcs[4] = {wb1, wb2, wb3, wb4};
    src = srcs[li - 1] + (size_t)b * 257 * H;
    dst = w14p + ((size_t)(li - 1) * 16 + b) * 65536;
  }
  __shared__ float tile[32][33];
  int t = threadIdx.x;
  int tx = t & 31, ty = t >> 5;
#pragma unroll
  for (int i = 0; i < 4; ++i) {
    int k = k0 + ty + i * 8;
    tile[ty + i * 8][tx] = (k < Ks) ? src[(size_t)k * H + n0 + tx] : 0.f;
  }
  if (k0 == 0 && ty == 0)
    biases[((size_t)li * 16 + b) * H + n0 + tx] = src[(size_t)Ks * H + n0 + tx];
  __syncthreads();
  if (t < 128) {
    int nn = t & 31, kg = t >> 5;
    int n = n0 + nn;
    int kt = k0 >> 5;
    union { unsigned short us[8]; s16x8 v; } pk;
#pragma unroll
    for (int j = 0; j < 8; ++j) pk.us[j] = f2bf(tile[kg * 8 + j][nn]);
    *(s16x8*)&dst[(size_t)(kt * 16 + (n >> 4)) * 512 + (kg * 16 + (n & 15)) * 8] = pk.v;
  }
}

// ---------------------------------------------------------------------------
// One fused Linear+ReLU layer. Wave (wr,wc): rows [wr*32,+32) x cols
// [wc*128,+128).  acc[2][8].  frag(kt,ct) byte off = kt*16384 + ct*1024
// from fpb (=pack base + wc*8192 + lane*16); fpb2 = fpb + 4096 for ct 4-7.
// A-op (weights): lane holds W^T[wc*128+ct*16+rlane][kt*32+kgrp*8 ..+7]
// B-op (h):       lane holds h[wr*32+rt*16+rlane][same k]
// C: m = wr*32+rt*16+(l&15), n = wc*128+ct*16+(l>>4)*4+reg
// wfA caller-persistent: entry = this layer's kt0 ct0-3; exit (non-LAST)
// = next layer's kt0 ct0-3 (in flight across barriers).
// ---------------------------------------------------------------------------
template <int NKT, bool LAST>
static __device__ __forceinline__ void mlp_layer(
    const char* fpb, const char* fpn, const float* __restrict__ bl,
    unsigned short* __restrict__ h_s, const float* __restrict__ wout_s,
    const int rlane, const int kgrp, const int wr, const int wc, const int l,
    s16x8 (&wfA)[4], float* psum) {
  static_assert((NKT & 1) == 0, "parity needs even NKT");
  f32x4 acc[2][8];
#pragma unroll
  for (int ct = 0; ct < 8; ++ct) {
    f32x4 bini = *(const f32x4*)(bl + wc * 128 + ct * 16 + kgrp * 4);
    acc[0][ct] = bini;
    acc[1][ct] = bini;
  }

  const char* fpb2 = fpb + 4096;

  // h ds_read bases: parity trick hswz(r, c+8) = hswz(r, c) + 8
  const char* hb = (const char*)h_s;
  const unsigned be = wr * 16384 + rlane * 512 + hswz(rlane, kgrp) * 16;
  const unsigned bo = wr * 16384 + rlane * 512 + hswz(rlane, 4 + kgrp) * 16;

  // h fragments double-buffered by kt parity
  s16x8 af[2][2];
  af[0][0] = *(const s16x8*)(hb + be);
  af[0][1] = *(const s16x8*)(hb + be + 8192);

#pragma unroll
  for (int kt = 0; kt < NKT; ++kt) {
    // this kt's ct4-7 frags
    s16x8 wfB[4];
#pragma unroll
    for (int c = 0; c < 4; ++c)
      wfB[c] = *(const s16x8*)(fpb2 + c * 1024);
    fpb2 += 16384;
    __builtin_amdgcn_s_setprio(1);
#pragma unroll
    for (int rt = 0; rt < 2; ++rt)
#pragma unroll
      for (int c = 0; c < 4; ++c)
        acc[rt][c] = __builtin_amdgcn_mfma_f32_16x16x32_bf16(
            wfA[c], af[kt & 1][rt], acc[rt][c], 0, 0, 0);
    __builtin_amdgcn_s_setprio(0);

    // prefetch next kt's ct0-3 + next kt's h frags (or next layer's kt0)
    if (kt + 1 < NKT) {
      fpb += 16384;
#pragma unroll
      for (int c = 0; c < 4; ++c)
        wfA[c] = *(const s16x8*)(fpb + c * 1024);
      const int p1 = (kt + 1) & 1;
      const unsigned base = p1 ? bo : be;
      const unsigned off = ((kt + 1) >> 1) * 128;
      af[p1][0] = *(const s16x8*)(hb + base + off);
      af[p1][1] = *(const s16x8*)(hb + base + off + 8192);
    } else if (!LAST) {
#pragma unroll
      for (int c = 0; c < 4; ++c)
        wfA[c] = *(const s16x8*)(fpn + c * 1024);
    }
    __builtin_amdgcn_s_setprio(1);
#pragma unroll
    for (int rt = 0; rt < 2; ++rt)
#pragma unroll
      for (int c = 0; c < 4; ++c)
        acc[rt][c + 4] = __builtin_amdgcn_mfma_f32_16x16x32_bf16(
            wfB[c], af[kt & 1][rt], acc[rt][c + 4], 0, 0, 0);
    __builtin_amdgcn_s_setprio(0);
  }

  if constexpr (LAST) {
    // folded projection: p[rt] = sum_n relu(h[m][n]) * wout[n] over wave cols
    float p[2];
#pragma unroll
    for (int rt = 0; rt < 2; ++rt) {
      float s = 0.f;
#pragma unroll
      for (int ct = 0; ct < 8; ++ct) {
        f32x4 wv = *(const f32x4*)(wout_s + wc * 128 + ct * 16 + kgrp * 4);
#pragma unroll
        for (int g = 0; g < 4; ++g)
          s += fmaxf(acc[rt][ct][g], 0.f) * wv[g];
      }
      s += __shfl_xor(s, 16);
      s += __shfl_xor(s, 32);
      p[rt] = s;
    }
    if (l < 16) {
      const int wbase = (wr * 2 + wc) * 32;
      psum[wbase + l]      = p[0];
      psum[wbase + 16 + l] = p[1];
    }
  } else {
    bar_raw();   // h reads consumed by MFMAs; vmcnt NOT drained
    // epilogue: ReLU + pack 4 bf16 -> b64 store  h[m][n0..n0+3]
    const int sub = (kgrp & 1) * 4;
    const int cbase = wc * 16 + (kgrp >> 1);
#pragma unroll
    for (int rt = 0; rt < 2; ++rt) {
      const int m = wr * 32 + rt * 16 + rlane;
      const int rowb = m * 256;
#pragma unroll
      for (int ct = 0; ct < 8; ++ct) {
        const int cs = hswz(m, cbase + ct * 2);
        float v0 = fmaxf(acc[rt][ct][0], 0.f);
        float v1 = fmaxf(acc[rt][ct][1], 0.f);
        float v2 = fmaxf(acc[rt][ct][2], 0.f);
        float v3 = fmaxf(acc[rt][ct][3], 0.f);
        union { __hip_bfloat162 h2[2]; uint2 u; } pk;
        pk.h2[0] = __float22bfloat162_rn(float2{v0, v1});
        pk.h2[1] = __float22bfloat162_rn(float2{v2, v3});
        *(uint2*)&h_s[rowb + cs * 8 + sub] = pk.u;
      }
    }
    bar_lgkm();  // DS writes visible; vmcnt untouched
  }
}

// ---------------------------------------------------------------------------
__global__ __launch_bounds__(256, 3) void hyponerf_main(
    const float* __restrict__ x, const float* __restrict__ rfreq,
    const float* __restrict__ wbout,
    const unsigned short* __restrict__ w0p, const unsigned short* __restrict__ w14p,
    const float* __restrict__ biases, float* __restrict__ out) {
  __shared__ __align__(16) unsigned short h_s[MT * 256];  // 32768 B
  __shared__ float fr_s[PE_NF * 3];
  __shared__ float x_s[MT * 3];
  __shared__ float wout_s[H + 1];
  __shared__ float psum[4 * 32];

  // XCD-aware swizzle: 4096 blocks, 8 XCDs -> contiguous batches per XCD
  int bid = blockIdx.x;
  int logical = (bid & 7) * 512 + (bid >> 3);
  int b  = logical >> 8;
  int mt = logical & 255;

  int t = threadIdx.x;
  int w = t >> 6, l = t & 63;
  int rlane = l & 15;
  int kgrp  = l >> 4;
  int wr = w >> 1, wc = w & 1;

  // fragment stream bases (col-half + lane offsets), bytes
  const size_t lane_off = (size_t)wc * 8192 + (size_t)l * 16;
  const char* f0 = (const char*)(w0p + (size_t)b * 32768) + lane_off;
  const char* f1 = (const char*)(w14p + (size_t)(0 * 16 + b) * 65536) + lane_off;
  const char* f2 = (const char*)(w14p + (size_t)(1 * 16 + b) * 65536) + lane_off;
  const char* f3 = (const char*)(w14p + (size_t)(2 * 16 + b) * 65536) + lane_off;
  const char* f4 = (const char*)(w14p + (size_t)(3 * 16 + b) * 65536) + lane_off;

  // issue layer0 kt0 ct0-3 weight frags NOW; hides under staging + PE
  s16x8 wfA[4];
#pragma unroll
  for (int c = 0; c < 4; ++c) wfA[c] = *(const s16x8*)(f0 + c * 1024);

  const float* xg = x + ((size_t)b * 16384 + (size_t)mt * MT) * 3;
  for (int i = t; i < MT * 3; i += 256) x_s[i] = xg[i];
  for (int i = t; i < PE_NF * 3; i += 256) fr_s[i] = rfreq[i] * 20.0f;
  for (int i = t; i < H + 1; i += 256) wout_s[i] = wbout[(size_t)b * (H + 1) + i];
  bar_lgkm();   // staging visible; vmcnt NOT drained

  // ---- Gaussian PE, chunk-owned b128 stores: thread (r = t>>2, q = t&3)
  {
    int r = t >> 2;
    int q = t & 3;
    float x0 = x_s[r * 3 + 0], x1 = x_s[r * 3 + 1], x2 = x_s[r * 3 + 2];
    int rowb = r * 256;
#pragma unroll
    for (int cc = 0; cc < 4; ++cc) {
      int ch = q * 4 + cc;
      union { unsigned short us[8]; s16x8 v; } pk;
#pragma unroll
      for (int j = 0; j < 8; ++j) {
        int n = ch * 8 + j;
        float v = 0.f;
        if (n < 60) {
          float kv = x0 * fr_s[n * 3] + x1 * fr_s[n * 3 + 1] + x2 * fr_s[n * 3 + 2];
          v = __sinf(kv);
        } else if (n < 120) {
          int f = n - 60;
          float kv = x0 * fr_s[f * 3] + x1 * fr_s[f * 3 + 1] + x2 * fr_s[f * 3 + 2];
          v = __cosf(kv);
        }
        pk.us[j] = f2bf(v);
      }
      *(s16x8*)&h_s[rowb + hswz(r, ch) * 8] = pk.v;
    }
  }
  bar_lgkm();   // PE writes visible; layer0 frags still in flight

  // ---- 5 fused Linear+ReLU layers (wfA carries next layer's kt0 ct0-3)
  const float* bb = biases + (size_t)b * H;
  mlp_layer<4, false>(f0, f1, bb + 0 * 16 * H, h_s, wout_s, rlane, kgrp,
                      wr, wc, l, wfA, psum);
  mlp_layer<8, false>(f1, f2, bb + 1 * 16 * H, h_s, wout_s, rlane, kgrp,
                      wr, wc, l, wfA, psum);
  mlp_layer<8, false>(f2, f3, bb + 2 * 16 * H, h_s, wout_s, rlane, kgrp,
                      wr, wc, l, wfA, psum);
  mlp_layer<8, false>(f3, f4, bb + 3 * 16 * H, h_s, wout_s, rlane, kgrp,
                      wr, wc, l, wfA, psum);
  mlp_layer<8, true >(f4, f4, bb + 4 * 16 * H, h_s, wout_s, rlane, kgrp,
                      wr, wc, l, wfA, psum);

  // ---- gather: out[row] = psum[wr*2][ri] + psum[wr*2+1][ri] + bias_out
  bar_lgkm();
  if (t < MT) {
    int wrg = t >> 5, ri = t & 31;
    float s = psum[(wrg * 2) * 32 + ri] + psum[(wrg * 2 + 1) * 32 + ri];
    out[(size_t)b * 16384 + (size_t)mt * MT + t] = s + wout_s[H];
  }
}

// ---------------------------------------------------------------------------
extern "C" void kernel_launch(void* const* d_in, const int* in_sizes, int n_in,
                              void* d_out, int out_size, void* d_ws, size_t ws_size,
                              hipStream_t stream) {
  const float* x     = (const float*)d_in[0];
  const float* wb0   = (const float*)d_in[1];
  const float* wb1   = (const float*)d_in[2];
  const float* wb2   = (const float*)d_in[3];
  const float* wb3   = (const float*)d_in[4];
  const float* wb4   = (const float*)d_in[5];
  const float* wbout = (const float*)d_in[6];
  const float* rfreq = (const float*)d_in[7];
  float* out = (float*)d_out;

  char* ws = (char*)d_ws;
  unsigned short* w0p  = (unsigned short*)ws;                                // 16 x 32768 bf16
  unsigned short* w14p = (unsigned short*)(ws + (size_t)16 * 32768 * 2);     // 64 x 65536 bf16
  float* biases = (float*)(ws + (size_t)16 * 32768 * 2
                              + (size_t)64 * 65536 * 2);                     // [5][16][256] f32

  prep_weights<<<dim3(8, 8, 80), 256, 0, stream>>>(wb0, wb1, wb2, wb3, wb4,
                                                   w0p, w14p, biases);
  hyponerf_main<<<dim3(4096), 256, 0, stream>>>(x, rfreq, wbout, w0p, w14p,
                                                biases, out);
}

// Round 13
// 174.810 us; speedup vs baseline: 1.0871x; 1.0871x over previous
//
#include <hip/hip_runtime.h>
#include <hip/hip_bf16.h>

// HypoNerf fused MLP on MI355X (gfx950). R13 = R10 squeezed to 4 blocks/CU.
//  R12 ledger: MFMA 179k / L1 136k / DS ~150k cy per CU vs 398k wall -- all
//  pipes ~balanced; only block-level TLP can overlap the serial phases
//  (PE, epilogues, barriers). R10 ran 3 waves/SIMD (148 unified regs).
//  To fit 128 regs -> 4 waves/SIMD:
//   - af single-buffer JIT (-16 regs): LDS latency hidden by TLP
//   - folded projection reads wout from LDS (-16)
//   - weights as ONE contiguous per-batch stream (5 layers, 576KB,
//     fragment-ordered): single running pointer, +16KB/kt, across the
//     whole layer chain (-8 addressing regs; cross-layer prefetch = free)
//  Everything else identical to R10 (165.7us anchor): MT=64, col-split
//  waves, 16x16x32 MFMA, parity DS bases, raw barriers, XCD swizzle.

#define H 256
#define MT 64
#define PE_NF 60

typedef __attribute__((ext_vector_type(8))) short s16x8;   // 8 bf16
typedef __attribute__((ext_vector_type(4))) float f32x4;   // MFMA acc

#define BATCH_BYTES (size_t)589824   // 576KB: 64KB (l0) + 4*128KB
#define BATCH_ELEMS (size_t)294912

static __device__ __forceinline__ unsigned short f2bf(float v) {
  unsigned int u = __float_as_uint(v);
  return (unsigned short)((u + 0x7FFFu + ((u >> 16) & 1u)) >> 16);
}
// swizzled 16B-chunk index within a 256-elem (32-chunk) row
static __device__ __forceinline__ int hswz(int row, int chunk) {
  return (chunk & ~7) | ((chunk ^ row) & 7);
}

static __device__ __forceinline__ void bar_raw() {
  asm volatile("s_barrier" ::: "memory");
}
static __device__ __forceinline__ void bar_lgkm() {
  asm volatile("s_waitcnt lgkmcnt(0)\n\ts_barrier" ::: "memory");
}

// ---------------------------------------------------------------------------
// Prep: wb (fp32, [K+1][H], last row bias) -> per-batch contiguous
// fragment-packed bf16 stream.  Within a layer, frag id = kt*16 + (n>>4);
// within frag: idx = (kgrp*16 + (n&15))*8 + (k&7).  Layer li starts at
// elem offset {0, 32768, 98304, 163840, 229376}[li] in the batch blob.
// ---------------------------------------------------------------------------
__global__ __launch_bounds__(256) void prep_weights(
    const float* __restrict__ wb0, const float* __restrict__ wb1,
    const float* __restrict__ wb2, const float* __restrict__ wb3,
    const float* __restrict__ wb4,
    unsigned short* __restrict__ wpk, float* __restrict__ biases) {
  int z = blockIdx.z;
  int li = z >> 4, b = z & 15;
  int k0 = blockIdx.x * 32;
  int n0 = blockIdx.y * 32;
  int Ks;
  const float* src;
  unsigned short* dst;
  if (li == 0) {
    Ks = 120;
    if (k0 >= 128) return;
    src = wb0 + (size_t)b * 121 * H;
    dst = wpk + b * BATCH_ELEMS;
  } else {
    Ks = 256;
    const float* srcs[4] = {wb1, wb2, wb3, wb4};
    src = srcs[li - 1] + (size_t)b * 257 * H;
    dst = wpk + b * BATCH_ELEMS + 32768 + (size_t)(li - 1) * 65536;
  }
  __shared__ float tile[32][33];
  int t = threadIdx.x;
  int tx = t & 31, ty = t >> 5;
#pragma unroll
  for (int i = 0; i < 4; ++i) {
    int k = k0 + ty + i * 8;
    tile[ty + i * 8][tx] = (k < Ks) ? src[(size_t)k * H + n0 + tx] : 0.f;
  }
  if (k0 == 0 && ty == 0)
    biases[((size_t)li * 16 + b) * H + n0 + tx] = src[(size_t)Ks * H + n0 + tx];
  __syncthreads();
  if (t < 128) {
    int nn = t & 31, kg = t >> 5;
    int n = n0 + nn;
    int kt = k0 >> 5;
    union { unsigned short us[8]; s16x8 v; } pk;
#pragma unroll
    for (int j = 0; j < 8; ++j) pk.us[j] = f2bf(tile[kg * 8 + j][nn]);
    *(s16x8*)&dst[(size_t)(kt * 16 + (n >> 4)) * 512 + (kg * 16 + (n & 15)) * 8] = pk.v;
  }
}

// ---------------------------------------------------------------------------
// One fused Linear+ReLU layer. Wave wc: all 64 rows x cols [wc*64,+64).
// acc[4][4]. fp = running stream pointer (already incl. wc*4096 + l*16),
// pointing at the NEXT kt's 4 frags; advances +16KB per kt across layers.
// On entry wf[0] holds this layer's kt0 frags.
// A-op (weights): lane holds W^T[wc*64+ct*16+rlane][kt*32+kgrp*8 ..+7]
// B-op (h):       lane holds h[rt*16+rlane][same k]
// C: m = rt*16+(l&15), n = wc*64+ct*16+(l>>4)*4+reg
// ---------------------------------------------------------------------------
template <int NKT, bool LAST>
static __device__ __forceinline__ void mlp_layer(
    const char*& fp, const float* __restrict__ bl,
    unsigned short* __restrict__ h_s, const float* __restrict__ wout_s,
    const int rlane, const int kgrp, const int wc, const int l,
    s16x8 (&wf)[2][4], float* psum) {
  static_assert((NKT & 1) == 0, "parity needs even NKT");
  f32x4 acc[4][4];
#pragma unroll
  for (int ct = 0; ct < 4; ++ct) {
    f32x4 bini = *(const f32x4*)(bl + wc * 64 + ct * 16 + kgrp * 4);
#pragma unroll
    for (int rt = 0; rt < 4; ++rt) acc[rt][ct] = bini;
  }

  // h ds_read bases: parity trick hswz(r, c+8) = hswz(r, c) + 8
  const char* hb = (const char*)h_s;
  const unsigned be = rlane * 512 + hswz(rlane, kgrp) * 16;
  const unsigned bo = rlane * 512 + hswz(rlane, 4 + kgrp) * 16;

#pragma unroll
  for (int kt = 0; kt < NKT; ++kt) {
    // JIT h fragments for this kt (single buffer; TLP hides LDS latency)
    s16x8 af[4];
    const unsigned base = ((kt & 1) ? bo : be) + (kt >> 1) * 128;
#pragma unroll
    for (int rt = 0; rt < 4; ++rt)
      af[rt] = *(const s16x8*)(hb + base + rt * 8192);

    // stream-prefetch the next kt's weight frags (next layer's kt0 at the
    // layer boundary -- the stream is contiguous). Skip only at chain end.
    if (!(LAST && kt == NKT - 1)) {
#pragma unroll
      for (int c = 0; c < 4; ++c)
        wf[(kt + 1) & 1][c] = *(const s16x8*)(fp + c * 1024);
      fp += 16384;
    }
    __builtin_amdgcn_s_setprio(1);
#pragma unroll
    for (int rt = 0; rt < 4; ++rt)
#pragma unroll
      for (int ct = 0; ct < 4; ++ct)
        acc[rt][ct] = __builtin_amdgcn_mfma_f32_16x16x32_bf16(
            wf[kt & 1][ct], af[rt], acc[rt][ct], 0, 0, 0);
    __builtin_amdgcn_s_setprio(0);
  }

  if constexpr (LAST) {
    // folded projection: p[rt] = sum_n relu(h[m][n]) * wout[n] (wout in LDS)
    float p[4];
#pragma unroll
    for (int rt = 0; rt < 4; ++rt) {
      float s = 0.f;
#pragma unroll
      for (int ct = 0; ct < 4; ++ct) {
        f32x4 wv = *(const f32x4*)(wout_s + wc * 64 + ct * 16 + kgrp * 4);
#pragma unroll
        for (int g = 0; g < 4; ++g)
          s += fmaxf(acc[rt][ct][g], 0.f) * wv[g];
      }
      s += __shfl_xor(s, 16);
      s += __shfl_xor(s, 32);
      p[rt] = s;
    }
    if (l < 16) {
#pragma unroll
      for (int rt = 0; rt < 4; ++rt)
        psum[wc * 64 + rt * 16 + l] = p[rt];
    }
  } else {
    bar_raw();   // h reads consumed by MFMAs; vmcnt NOT drained
    // epilogue: ReLU + pack 4 bf16 -> b64 store  h[m][n0..n0+3]
    const int sub = (kgrp & 1) * 4;
    const int cbase = wc * 8 + (kgrp >> 1);
#pragma unroll
    for (int rt = 0; rt < 4; ++rt) {
      const int m = rt * 16 + rlane;
      const int rowb = m * 256;
#pragma unroll
      for (int ct = 0; ct < 4; ++ct) {
        const int cs = hswz(m, cbase + ct * 2);
        float v0 = fmaxf(acc[rt][ct][0], 0.f);
        float v1 = fmaxf(acc[rt][ct][1], 0.f);
        float v2 = fmaxf(acc[rt][ct][2], 0.f);
        float v3 = fmaxf(acc[rt][ct][3], 0.f);
        union { __hip_bfloat162 h2[2]; uint2 u; } pk;
        pk.h2[0] = __float22bfloat162_rn(float2{v0, v1});
        pk.h2[1] = __float22bfloat162_rn(float2{v2, v3});
        *(uint2*)&h_s[rowb + cs * 8 + sub] = pk.u;
      }
    }
    bar_lgkm();  // DS writes visible; vmcnt untouched
  }
}

// ---------------------------------------------------------------------------
__global__ __launch_bounds__(256, 4) void hyponerf_main(
    const float* __restrict__ x, const float* __restrict__ rfreq,
    const float* __restrict__ wbout, const unsigned short* __restrict__ wpk,
    const float* __restrict__ biases, float* __restrict__ out) {
  __shared__ __align__(16) unsigned short h_s[MT * 256];  // 32768 B
  __shared__ float fr_s[PE_NF * 3];
  __shared__ float x_s[MT * 3];
  __shared__ float wout_s[H + 1];
  __shared__ float psum[4 * 64];

  // XCD-aware swizzle: 4096 blocks, 8 XCDs -> contiguous batches per XCD
  int bid = blockIdx.x;
  int logical = (bid & 7) * 512 + (bid >> 3);
  int b  = logical >> 8;
  int mt = logical & 255;

  int t = threadIdx.x;
  int wc = t >> 6, l = t & 63;
  int rlane = l & 15;
  int kgrp  = l >> 4;

  // single running weight-stream pointer (batch blob + wave-col + lane)
  const char* fp = (const char*)wpk + b * BATCH_BYTES
                 + (size_t)wc * 4096 + (size_t)l * 16;

  // issue layer0 kt0 frags NOW; latency hides under staging + PE
  s16x8 wf[2][4];
#pragma unroll
  for (int c = 0; c < 4; ++c) wf[0][c] = *(const s16x8*)(fp + c * 1024);
  fp += 16384;

  const float* xg = x + ((size_t)b * 16384 + (size_t)mt * MT) * 3;
  for (int i = t; i < MT * 3; i += 256) x_s[i] = xg[i];
  for (int i = t; i < PE_NF * 3; i += 256) fr_s[i] = rfreq[i] * 20.0f;
  for (int i = t; i < H + 1; i += 256) wout_s[i] = wbout[(size_t)b * (H + 1) + i];
  bar_lgkm();   // staging visible; vmcnt NOT drained

  // ---- Gaussian PE, chunk-owned b128 stores: thread (r = t>>2, q = t&3)
  {
    int r = t >> 2;
    int q = t & 3;
    float x0 = x_s[r * 3 + 0], x1 = x_s[r * 3 + 1], x2 = x_s[r * 3 + 2];
    int rowb = r * 256;
#pragma unroll
    for (int cc = 0; cc < 4; ++cc) {
      int ch = q * 4 + cc;
      union { unsigned short us[8]; s16x8 v; } pk;
#pragma unroll
      for (int j = 0; j < 8; ++j) {
        int n = ch * 8 + j;
        float v = 0.f;
        if (n < 60) {
          float kv = x0 * fr_s[n * 3] + x1 * fr_s[n * 3 + 1] + x2 * fr_s[n * 3 + 2];
          v = __sinf(kv);
        } else if (n < 120) {
          int f = n - 60;
          float kv = x0 * fr_s[f * 3] + x1 * fr_s[f * 3 + 1] + x2 * fr_s[f * 3 + 2];
          v = __cosf(kv);
        }
        pk.us[j] = f2bf(v);
      }
      *(s16x8*)&h_s[rowb + hswz(r, ch) * 8] = pk.v;
    }
  }
  bar_lgkm();   // PE writes visible; layer0 frags still in flight

  // ---- 5 fused Linear+ReLU layers (fp streams through all of them)
  const float* bb = biases + (size_t)b * H;
  mlp_layer<4, false>(fp, bb + 0 * 16 * H, h_s, wout_s, rlane, kgrp, wc, l,
                      wf, psum);
  mlp_layer<8, false>(fp, bb + 1 * 16 * H, h_s, wout_s, rlane, kgrp, wc, l,
                      wf, psum);
  mlp_layer<8, false>(fp, bb + 2 * 16 * H, h_s, wout_s, rlane, kgrp, wc, l,
                      wf, psum);
  mlp_layer<8, false>(fp, bb + 3 * 16 * H, h_s, wout_s, rlane, kgrp, wc, l,
                      wf, psum);
  mlp_layer<8, true >(fp, bb + 4 * 16 * H, h_s, wout_s, rlane, kgrp, wc, l,
                      wf, psum);

  // ---- gather: out[r] = sum_wc psum[wc][r] + bias_out
  bar_lgkm();
  if (t < MT) {
    float s = psum[t] + psum[64 + t] + psum[128 + t] + psum[192 + t];
    out[(size_t)b * 16384 + (size_t)mt * MT + t] = s + wout_s[H];
  }
}

// ---------------------------------------------------------------------------
extern "C" void kernel_launch(void* const* d_in, const int* in_sizes, int n_in,
                              void* d_out, int out_size, void* d_ws, size_t ws_size,
                              hipStream_t stream) {
  const float* x     = (const float*)d_in[0];
  const float* wb0   = (const float*)d_in[1];
  const float* wb1   = (const float*)d_in[2];
  const float* wb2   = (const float*)d_in[3];
  const float* wb3   = (const float*)d_in[4];
  const float* wb4   = (const float*)d_in[5];
  const float* wbout = (const float*)d_in[6];
  const float* rfreq = (const float*)d_in[7];
  float* out = (float*)d_out;

  char* ws = (char*)d_ws;
  unsigned short* wpk = (unsigned short*)ws;                    // 16 x 576KB
  float* biases = (float*)(ws + 16 * BATCH_BYTES);              // [5][16][256]

  prep_weights<<<dim3(8, 8, 80), 256, 0, stream>>>(wb0, wb1, wb2, wb3, wb4,
                                                   wpk, biases);
  hyponerf_main<<<dim3(4096), 256, 0, stream>>>(x, rfreq, wbout, wpk,
                                                biases, out);
}

// Round 14
// 168.218 us; speedup vs baseline: 1.1297x; 1.0392x over previous
//
#include <hip/hip_runtime.h>
#include <hip/hip_bf16.h>

// HypoNerf fused MLP on MI355X (gfx950). R14 = R13 minus the spill.
//  R13: 4 blocks/CU worked (occupancy 30->39%) but wf[2][4]+af+acc blew the
//  128-reg cap -> 95MB scratch. Fix: single wf[4] buffer with loads placed
//  AFTER the MFMA cluster that consumes wf (MFMA reads operands at issue,
//  so the loads overlap the 16-MFMA cluster = double-buffer effect at
//  single-buffer cost). #pragma unroll 2 caps SSA renaming; contiguous
//  weight stream means "load next 16KB" IS the next layer's kt0 (the single
//  end-of-chain overrun lands in the biases region of ws -- harmless).
//  Steady regs: acc 64 + wf 16 + af 16 + ~15 addr = ~111 < 128.

#define H 256
#define MT 64
#define PE_NF 60

typedef __attribute__((ext_vector_type(8))) short s16x8;   // 8 bf16
typedef __attribute__((ext_vector_type(4))) float f32x4;   // MFMA acc

#define BATCH_BYTES (size_t)589824   // 576KB: 64KB (l0) + 4*128KB
#define BATCH_ELEMS (size_t)294912

static __device__ __forceinline__ unsigned short f2bf(float v) {
  unsigned int u = __float_as_uint(v);
  return (unsigned short)((u + 0x7FFFu + ((u >> 16) & 1u)) >> 16);
}
// swizzled 16B-chunk index within a 256-elem (32-chunk) row
static __device__ __forceinline__ int hswz(int row, int chunk) {
  return (chunk & ~7) | ((chunk ^ row) & 7);
}

static __device__ __forceinline__ void bar_raw() {
  asm volatile("s_barrier" ::: "memory");
}
static __device__ __forceinline__ void bar_lgkm() {
  asm volatile("s_waitcnt lgkmcnt(0)\n\ts_barrier" ::: "memory");
}

// ---------------------------------------------------------------------------
// Prep: wb (fp32, [K+1][H], last row bias) -> per-batch contiguous
// fragment-packed bf16 stream (R13 format).  Within a layer, frag id =
// kt*16 + (n>>4); within frag: idx = (kgrp*16 + (n&15))*8 + (k&7).
// Layer li starts at elem offset {0,32768,98304,163840,229376}[li].
// ---------------------------------------------------------------------------
__global__ __launch_bounds__(256) void prep_weights(
    const float* __restrict__ wb0, const float* __restrict__ wb1,
    const float* __restrict__ wb2, const float* __restrict__ wb3,
    const float* __restrict__ wb4,
    unsigned short* __restrict__ wpk, float* __restrict__ biases) {
  int z = blockIdx.z;
  int li = z >> 4, b = z & 15;
  int k0 = blockIdx.x * 32;
  int n0 = blockIdx.y * 32;
  int Ks;
  const float* src;
  unsigned short* dst;
  if (li == 0) {
    Ks = 120;
    if (k0 >= 128) return;
    src = wb0 + (size_t)b * 121 * H;
    dst = wpk + b * BATCH_ELEMS;
  } else {
    Ks = 256;
    const float* srcs[4] = {wb1, wb2, wb3, wb4};
    src = srcs[li - 1] + (size_t)b * 257 * H;
    dst = wpk + b * BATCH_ELEMS + 32768 + (size_t)(li - 1) * 65536;
  }
  __shared__ float tile[32][33];
  int t = threadIdx.x;
  int tx = t & 31, ty = t >> 5;
#pragma unroll
  for (int i = 0; i < 4; ++i) {
    int k = k0 + ty + i * 8;
    tile[ty + i * 8][tx] = (k < Ks) ? src[(size_t)k * H + n0 + tx] : 0.f;
  }
  if (k0 == 0 && ty == 0)
    biases[((size_t)li * 16 + b) * H + n0 + tx] = src[(size_t)Ks * H + n0 + tx];
  __syncthreads();
  if (t < 128) {
    int nn = t & 31, kg = t >> 5;
    int n = n0 + nn;
    int kt = k0 >> 5;
    union { unsigned short us[8]; s16x8 v; } pk;
#pragma unroll
    for (int j = 0; j < 8; ++j) pk.us[j] = f2bf(tile[kg * 8 + j][nn]);
    *(s16x8*)&dst[(size_t)(kt * 16 + (n >> 4)) * 512 + (kg * 16 + (n & 15)) * 8] = pk.v;
  }
}

// ---------------------------------------------------------------------------
// One fused Linear+ReLU layer. Wave wc: all 64 rows x cols [wc*64,+64).
// acc[4][4]. fp = running stream pointer (incl. wc*4096 + l*16); advances
// +16KB per kt continuously across ALL layers (the stream is contiguous,
// so the post-MFMA load of "next 16KB" is the next kt or next layer's kt0).
// On entry wf holds this layer's kt0 frags; on exit wf holds the next
// layer's kt0 frags (end-of-chain overrun reads biases region: harmless).
// A-op (weights): lane holds W^T[wc*64+ct*16+rlane][kt*32+kgrp*8 ..+7]
// B-op (h):       lane holds h[rt*16+rlane][same k]
// C: m = rt*16+(l&15), n = wc*64+ct*16+(l>>4)*4+reg
// ---------------------------------------------------------------------------
template <int NKT, bool LAST>
static __device__ __forceinline__ void mlp_layer(
    const char*& fp, const float* __restrict__ bl,
    unsigned short* __restrict__ h_s, const float* __restrict__ wout_s,
    const int rlane, const int kgrp, const int wc, const int l,
    s16x8 (&wf)[4], float* psum) {
  static_assert((NKT & 1) == 0, "parity needs even NKT");
  f32x4 acc[4][4];
#pragma unroll
  for (int ct = 0; ct < 4; ++ct) {
    f32x4 bini = *(const f32x4*)(bl + wc * 64 + ct * 16 + kgrp * 4);
#pragma unroll
    for (int rt = 0; rt < 4; ++rt) acc[rt][ct] = bini;
  }

  // h ds_read bases: parity trick hswz(r, c+8) = hswz(r, c) + 8
  const char* hb = (const char*)h_s;
  const unsigned be = rlane * 512 + hswz(rlane, kgrp) * 16;
  const unsigned bo = rlane * 512 + hswz(rlane, 4 + kgrp) * 16;

  unsigned koff = 0;
#pragma unroll 2
  for (int kt = 0; kt < NKT; ++kt) {
    // JIT h fragments for this kt (TLP across 4 independent blocks/CU
    // hides LDS latency)
    s16x8 af[4];
    const unsigned base = ((kt & 1) ? bo : be) + koff;
#pragma unroll
    for (int rt = 0; rt < 4; ++rt)
      af[rt] = *(const s16x8*)(hb + base + rt * 8192);
    if (kt & 1) koff += 128;

    __builtin_amdgcn_s_setprio(1);
#pragma unroll
    for (int rt = 0; rt < 4; ++rt)
#pragma unroll
      for (int ct = 0; ct < 4; ++ct)
        acc[rt][ct] = __builtin_amdgcn_mfma_f32_16x16x32_bf16(
            wf[ct], af[rt], acc[rt][ct], 0, 0, 0);
    __builtin_amdgcn_s_setprio(0);

    // reload wf with the NEXT kt's frags (same registers: MFMAs above have
    // already read their operands at issue -> loads overlap the cluster)
#pragma unroll
    for (int c = 0; c < 4; ++c)
      wf[c] = *(const s16x8*)(fp + c * 1024);
    fp += 16384;
  }

  if constexpr (LAST) {
    // folded projection: p[rt] = sum_n relu(h[m][n]) * wout[n] (wout in LDS)
    float p[4];
#pragma unroll
    for (int rt = 0; rt < 4; ++rt) {
      float s = 0.f;
#pragma unroll
      for (int ct = 0; ct < 4; ++ct) {
        f32x4 wv = *(const f32x4*)(wout_s + wc * 64 + ct * 16 + kgrp * 4);
#pragma unroll
        for (int g = 0; g < 4; ++g)
          s += fmaxf(acc[rt][ct][g], 0.f) * wv[g];
      }
      s += __shfl_xor(s, 16);
      s += __shfl_xor(s, 32);
      p[rt] = s;
    }
    if (l < 16) {
#pragma unroll
      for (int rt = 0; rt < 4; ++rt)
        psum[wc * 64 + rt * 16 + l] = p[rt];
    }
  } else {
    bar_raw();   // h reads consumed by MFMAs; vmcnt NOT drained
    // epilogue: ReLU + pack 4 bf16 -> b64 store  h[m][n0..n0+3]
    const int sub = (kgrp & 1) * 4;
    const int cbase = wc * 8 + (kgrp >> 1);
#pragma unroll
    for (int rt = 0; rt < 4; ++rt) {
      const int m = rt * 16 + rlane;
      const int rowb = m * 256;
#pragma unroll
      for (int ct = 0; ct < 4; ++ct) {
        const int cs = hswz(m, cbase + ct * 2);
        float v0 = fmaxf(acc[rt][ct][0], 0.f);
        float v1 = fmaxf(acc[rt][ct][1], 0.f);
        float v2 = fmaxf(acc[rt][ct][2], 0.f);
        float v3 = fmaxf(acc[rt][ct][3], 0.f);
        union { __hip_bfloat162 h2[2]; uint2 u; } pk;
        pk.h2[0] = __float22bfloat162_rn(float2{v0, v1});
        pk.h2[1] = __float22bfloat162_rn(float2{v2, v3});
        *(uint2*)&h_s[rowb + cs * 8 + sub] = pk.u;
      }
    }
    bar_lgkm();  // DS writes visible; vmcnt untouched
  }
}

// ---------------------------------------------------------------------------
__global__ __launch_bounds__(256, 4) void hyponerf_main(
    const float* __restrict__ x, const float* __restrict__ rfreq,
    const float* __restrict__ wbout, const unsigned short* __restrict__ wpk,
    const float* __restrict__ biases, float* __restrict__ out) {
  __shared__ __align__(16) unsigned short h_s[MT * 256];  // 32768 B
  __shared__ float fr_s[PE_NF * 3];
  __shared__ float x_s[MT * 3];
  __shared__ float wout_s[H + 1];
  __shared__ float psum[4 * 64];

  // XCD-aware swizzle: 4096 blocks, 8 XCDs -> contiguous batches per XCD
  int bid = blockIdx.x;
  int logical = (bid & 7) * 512 + (bid >> 3);
  int b  = logical >> 8;
  int mt = logical & 255;

  int t = threadIdx.x;
  int wc = t >> 6, l = t & 63;
  int rlane = l & 15;
  int kgrp  = l >> 4;

  // single running weight-stream pointer (batch blob + wave-col + lane)
  const char* fp = (const char*)wpk + b * BATCH_BYTES
                 + (size_t)wc * 4096 + (size_t)l * 16;

  // issue layer0 kt0 frags NOW; latency hides under staging + PE
  s16x8 wf[4];
#pragma unroll
  for (int c = 0; c < 4; ++c) wf[c] = *(const s16x8*)(fp + c * 1024);
  fp += 16384;

  const float* xg = x + ((size_t)b * 16384 + (size_t)mt * MT) * 3;
  for (int i = t; i < MT * 3; i += 256) x_s[i] = xg[i];
  for (int i = t; i < PE_NF * 3; i += 256) fr_s[i] = rfreq[i] * 20.0f;
  for (int i = t; i < H + 1; i += 256) wout_s[i] = wbout[(size_t)b * (H + 1) + i];
  bar_lgkm();   // staging visible; vmcnt NOT drained

  // ---- Gaussian PE, chunk-owned b128 stores: thread (r = t>>2, q = t&3)
  {
    int r = t >> 2;
    int q = t & 3;
    float x0 = x_s[r * 3 + 0], x1 = x_s[r * 3 + 1], x2 = x_s[r * 3 + 2];
    int rowb = r * 256;
#pragma unroll
    for (int cc = 0; cc < 4; ++cc) {
      int ch = q * 4 + cc;
      union { unsigned short us[8]; s16x8 v; } pk;
#pragma unroll
      for (int j = 0; j < 8; ++j) {
        int n = ch * 8 + j;
        float v = 0.f;
        if (n < 60) {
          float kv = x0 * fr_s[n * 3] + x1 * fr_s[n * 3 + 1] + x2 * fr_s[n * 3 + 2];
          v = __sinf(kv);
        } else if (n < 120) {
          int f = n - 60;
          float kv = x0 * fr_s[f * 3] + x1 * fr_s[f * 3 + 1] + x2 * fr_s[f * 3 + 2];
          v = __cosf(kv);
        }
        pk.us[j] = f2bf(v);
      }
      *(s16x8*)&h_s[rowb + hswz(r, ch) * 8] = pk.v;
    }
  }
  bar_lgkm();   // PE writes visible; layer0 frags still in flight

  // ---- 5 fused Linear+ReLU layers (fp streams through all of them)
  const float* bb = biases + (size_t)b * H;
  mlp_layer<4, false>(fp, bb + 0 * 16 * H, h_s, wout_s, rlane, kgrp, wc, l,
                      wf, psum);
  mlp_layer<8, false>(fp, bb + 1 * 16 * H, h_s, wout_s, rlane, kgrp, wc, l,
                      wf, psum);
  mlp_layer<8, false>(fp, bb + 2 * 16 * H, h_s, wout_s, rlane, kgrp, wc, l,
                      wf, psum);
  mlp_layer<8, false>(fp, bb + 3 * 16 * H, h_s, wout_s, rlane, kgrp, wc, l,
                      wf, psum);
  mlp_layer<8, true >(fp, bb + 4 * 16 * H, h_s, wout_s, rlane, kgrp, wc, l,
                      wf, psum);

  // ---- gather: out[r] = sum_wc psum[wc][r] + bias_out
  bar_lgkm();
  if (t < MT) {
    float s = psum[t] + psum[64 + t] + psum[128 + t] + psum[192 + t];
    out[(size_t)b * 16384 + (size_t)mt * MT + t] = s + wout_s[H];
  }
}

// ---------------------------------------------------------------------------
extern "C" void kernel_launch(void* const* d_in, const int* in_sizes, int n_in,
                              void* d_out, int out_size, void* d_ws, size_t ws_size,
                              hipStream_t stream) {
  const float* x     = (const float*)d_in[0];
  const float* wb0   = (const float*)d_in[1];
  const float* wb1   = (const float*)d_in[2];
  const float* wb2   = (const float*)d_in[3];
  const float* wb3   = (const float*)d_in[4];
  const float* wb4   = (const float*)d_in[5];
  const float* wbout = (const float*)d_in[6];
  const float* rfreq = (const float*)d_in[7];
  float* out = (float*)d_out;

  char* ws = (char*)d_ws;
  unsigned short* wpk = (unsigned short*)ws;                    // 16 x 576KB
  float* biases = (float*)(ws + 16 * BATCH_BYTES);              // [5][16][256]

  prep_weights<<<dim3(8, 8, 80), 256, 0, stream>>>(wb0, wb1, wb2, wb3, wb4,
                                                   wpk, biases);
  hyponerf_main<<<dim3(4096), 256, 0, stream>>>(x, rfreq, wbout, wpk,
                                                biases, out);
}